// Round 4
// baseline (3611.104 us; speedup 1.0000x reference)
//
#include <hip/hip_runtime.h>

#define NNODES 100000
#define DDIM   512
#define NCLS   40
#define KPAD   56   // LDS bf16 row stride: 112B rows -> 16B-aligned frag reads, 2-way banks (free)

typedef unsigned short bf16_t;
// guide §3 compile-verified form on gfx950: bf16 MFMA fragments as short ext-vectors
typedef short bf16x8 __attribute__((ext_vector_type(8)));
typedef float f32x4  __attribute__((ext_vector_type(4)));

__device__ __forceinline__ bf16_t f2bf(float f){
    unsigned int u = __float_as_uint(f);
    u += 0x7fffu + ((u >> 16) & 1u);   // RNE
    return (bf16_t)(u >> 16);
}

// ---------------- setup kernels ----------------

__global__ void zero_int(int* __restrict__ p, int n){
    int i = blockIdx.x * 256 + threadIdx.x;
    if (i < n) p[i] = 0;
}

__global__ void count_deg(const int* __restrict__ src, const int* __restrict__ dst,
                          int* __restrict__ dout, int* __restrict__ din, int E){
    int i = blockIdx.x * 256 + threadIdx.x;
    if (i < E){
        atomicAdd(&dout[src[i]], 1);
        atomicAdd(&din[dst[i]], 1);
    }
}

__global__ void norm_k(const int* __restrict__ dout, const int* __restrict__ din,
                       float* __restrict__ nsrc, float* __restrict__ ndst, int n){
    int i = blockIdx.x * 256 + threadIdx.x;
    if (i < n){
        nsrc[i] = rsqrtf(fmaxf((float)dout[i], 1.f));
        ndst[i] = rsqrtf(fmaxf((float)din[i], 1.f));
    }
}

__global__ void scan_block(const int* __restrict__ in, int* __restrict__ out,
                           int* __restrict__ bsums, int n){
    __shared__ int tmp[1024];
    int t = threadIdx.x;
    int i = blockIdx.x * 1024 + t;
    int v = (i < n) ? in[i] : 0;
    tmp[t] = v; __syncthreads();
    for (int off = 1; off < 1024; off <<= 1){
        int x = (t >= off) ? tmp[t - off] : 0;
        __syncthreads();
        tmp[t] += x;
        __syncthreads();
    }
    if (i < n) out[i] = tmp[t] - v;           // exclusive
    if (bsums && t == 1023) bsums[blockIdx.x] = tmp[1023];
}

__global__ void add_offs(int* __restrict__ rp, int* __restrict__ cur,
                         const int* __restrict__ bsums, int n){
    int i = blockIdx.x * 1024 + threadIdx.x;
    if (i < n){
        int v = rp[i] + bsums[blockIdx.x];
        rp[i] = v;
        cur[i] = v;
    }
}

__global__ void fill_csr(const int* __restrict__ src, const int* __restrict__ dst,
                         int* __restrict__ cur, int* __restrict__ csr, int E){
    int i = blockIdx.x * 256 + threadIdx.x;
    if (i < E){
        int pos = atomicAdd(&cur[dst[i]], 1);
        csr[pos] = src[i];
    }
}

// W f32 [K,N] row-major -> WT bf16 [N,K] row-major (fused transpose + cast)
__global__ void transpose_w(const float* __restrict__ W, bf16_t* __restrict__ WT, int K, int N){
    int i = blockIdx.x * 256 + threadIdx.x;
    if (i < K * N){
        int k = i / N, n = i - k * N;
        WT[n * K + k] = f2bf(W[i]);
    }
}

// ---------------- GEMM: C = act(A @ B + bias) * rowscale ----------------
// A f32 [M,512]; BT bf16 [N,512] (B transposed); C f32 [M,N]. fp32 accumulate,
// bf16 MFMA inputs (A cast during LDS staging). 128x128 tile, 4 waves 2x2, 4x4 frags.

__global__ __launch_bounds__(256) void gemm_f32(
    const float* __restrict__ A, const bf16_t* __restrict__ BT,
    const float* __restrict__ bias, const float* __restrict__ rowscale,
    float* __restrict__ Cmat, int M, int N, int doRelu)
{
    const int K = DDIM;
    __shared__ __align__(16) bf16_t As[128 * KPAD];
    __shared__ __align__(16) bf16_t Bs[128 * KPAD];
    int tid = threadIdx.x;
    int m0 = blockIdx.x * 128, n0 = blockIdx.y * 128;
    int wave = tid >> 6, lane = tid & 63;
    int wm = (wave >> 1) * 64, wn = (wave & 1) * 64;
    int quad = lane >> 4, r16 = lane & 15;

    f32x4 acc[4][4];
    #pragma unroll
    for (int i = 0; i < 4; i++)
        #pragma unroll
        for (int j = 0; j < 4; j++)
            acc[i][j] = (f32x4){0.f, 0.f, 0.f, 0.f};

    for (int k0 = 0; k0 < K; k0 += 32){
        // A tile: 128x32 f32 = 1024 float4 slots; B tile: 128x32 bf16 = 512 uint4 slots
        float4 av[4];
        uint4  bv[2];
        #pragma unroll
        for (int j = 0; j < 4; j++){
            int slot = tid + j * 256;          // 0..1023
            int row = slot >> 3, c4 = slot & 7;
            av[j] = (float4){0.f, 0.f, 0.f, 0.f};
            if (m0 + row < M) av[j] = *(const float4*)(A + (size_t)(m0 + row) * K + k0 + c4 * 4);
        }
        #pragma unroll
        for (int j = 0; j < 2; j++){
            int slot = tid + j * 256;          // 0..511
            int row = slot >> 2, c8 = slot & 3;
            bv[j] = (uint4){0, 0, 0, 0};
            if (n0 + row < N) bv[j] = *(const uint4*)(BT + (size_t)(n0 + row) * K + k0 + c8 * 8);
        }
        __syncthreads();
        #pragma unroll
        for (int j = 0; j < 4; j++){
            int slot = tid + j * 256;
            int row = slot >> 3, c4 = slot & 7;
            ushort4 ap;
            ap.x = f2bf(av[j].x); ap.y = f2bf(av[j].y);
            ap.z = f2bf(av[j].z); ap.w = f2bf(av[j].w);
            *(ushort4*)&As[row * KPAD + c4 * 4] = ap;
        }
        #pragma unroll
        for (int j = 0; j < 2; j++){
            int slot = tid + j * 256;
            int row = slot >> 2, c8 = slot & 3;
            *(uint4*)&Bs[row * KPAD + c8 * 8] = bv[j];
        }
        __syncthreads();

        bf16x8 af[4], bfr[4];
        #pragma unroll
        for (int mi = 0; mi < 4; mi++)
            af[mi] = *(const bf16x8*)&As[(wm + mi * 16 + r16) * KPAD + quad * 8];
        #pragma unroll
        for (int ni = 0; ni < 4; ni++)
            bfr[ni] = *(const bf16x8*)&Bs[(wn + ni * 16 + r16) * KPAD + quad * 8];
        #pragma unroll
        for (int mi = 0; mi < 4; mi++)
            #pragma unroll
            for (int ni = 0; ni < 4; ni++)
                acc[mi][ni] = __builtin_amdgcn_mfma_f32_16x16x32_bf16(af[mi], bfr[ni], acc[mi][ni], 0, 0, 0);
    }

    // C/D layout: col = lane&15, row = quad*4 + reg  [m89/m91-verified]
    #pragma unroll
    for (int mi = 0; mi < 4; mi++){
        int rbase = m0 + wm + mi * 16 + quad * 4;
        #pragma unroll
        for (int ni = 0; ni < 4; ni++){
            int c = n0 + wn + ni * 16 + r16;
            if (c < N){
                float bvv = bias ? bias[c] : 0.f;
                #pragma unroll
                for (int r = 0; r < 4; r++){
                    int row = rbase + r;
                    if (row < M){
                        float val = acc[mi][ni][r] + bvv;
                        if (doRelu) val = fmaxf(val, 0.f);
                        if (rowscale) val *= rowscale[row];
                        Cmat[(size_t)row * N + c] = val;
                    }
                }
            }
        }
    }
}

// ---------------- SpMM (CSR by dst): out[v] = ndst[v] * sum_{u in N(v)} g[u], 512-dim f32 ----------------
// one wave per node; lane holds 8 f32 -> per edge the wave reads one contiguous 2 KB row.

__global__ __launch_bounds__(256) void spmm512(
    const float* __restrict__ g, const int* __restrict__ csr,
    const int* __restrict__ rp, const int* __restrict__ deg,
    const float* __restrict__ ndst, float* __restrict__ outm, int nn)
{
    int wave = threadIdx.x >> 6, lane = threadIdx.x & 63;
    int v = blockIdx.x * 4 + wave;
    if (v >= nn) return;
    int start = rp[v], cnt = deg[v];
    float acc[8] = {0,0,0,0,0,0,0,0};
    const float* base = g + (size_t)lane * 8;
    for (int e = 0; e < cnt; e++){
        int u = csr[start + e];
        const float* p = base + (size_t)u * DDIM;
        float4 d0 = *(const float4*)(p);
        float4 d1 = *(const float4*)(p + 4);
        acc[0] += d0.x; acc[1] += d0.y; acc[2] += d0.z; acc[3] += d0.w;
        acc[4] += d1.x; acc[5] += d1.y; acc[6] += d1.z; acc[7] += d1.w;
    }
    float s = ndst[v];
    float* o = outm + (size_t)v * DDIM + lane * 8;
    *(float4*)(o)     = (float4){acc[0]*s, acc[1]*s, acc[2]*s, acc[3]*s};
    *(float4*)(o + 4) = (float4){acc[4]*s, acc[5]*s, acc[6]*s, acc[7]*s};
}

// 40-dim SpMM for the last layer (GEMM commuted ahead of it): out = ndst*sum + b2
__global__ __launch_bounds__(256) void spmm40(
    const float* __restrict__ p40, const int* __restrict__ csr,
    const int* __restrict__ rp, const int* __restrict__ deg,
    const float* __restrict__ ndst, const float* __restrict__ b2,
    float* __restrict__ out, int nn)
{
    int wave = threadIdx.x >> 6, lane = threadIdx.x & 63;
    int v = blockIdx.x * 4 + wave;
    if (v >= nn || lane >= NCLS) return;
    int start = rp[v], cnt = deg[v];
    float acc = 0.f;
    for (int e = 0; e < cnt; e++){
        int u = csr[start + e];
        acc += p40[(size_t)u * NCLS + lane];
    }
    out[(size_t)v * NCLS + lane] = acc * ndst[v] + b2[lane];
}

// ---------------- launch ----------------
// f32 I/O per the reference (jnp.float32). ws use ~222 MB (round 1 ran with
// ~230 MB without fault). d_in[0] (features, 204.8 MB f32) is the h ping-pong
// partner after its last read — harness restores d_in before every launch.

extern "C" void kernel_launch(void* const* d_in, const int* in_sizes, int n_in,
                              void* d_out, int out_size, void* d_ws, size_t ws_size,
                              hipStream_t stream)
{
    const float* feat = (const float*)d_in[0];
    const int*   src  = (const int*)d_in[1];
    const int*   dst  = (const int*)d_in[2];
    const float* Wlin = (const float*)d_in[3];
    const float* blin = (const float*)d_in[4];
    const float* W0   = (const float*)d_in[5];
    const float* b0   = (const float*)d_in[6];
    const float* W1   = (const float*)d_in[7];
    const float* b1   = (const float*)d_in[8];
    const float* W2   = (const float*)d_in[9];
    const float* b2   = (const float*)d_in[10];

    const int NN = NNODES;
    const int E  = in_sizes[1];

    char* wsp = (char*)d_ws;
    auto alloc = [&](size_t bytes) -> char* {
        char* r = wsp;
        wsp += (bytes + 255) & ~(size_t)255;
        return r;
    };
    int*    deg_out = (int*)alloc((size_t)NN * 4);
    int*    deg_in  = (int*)alloc((size_t)NN * 4);
    float*  nsrc    = (float*)alloc((size_t)NN * 4);
    float*  ndst    = (float*)alloc((size_t)NN * 4);
    int*    row_ptr = (int*)alloc((size_t)NN * 4);
    int*    cursor  = (int*)alloc((size_t)NN * 4);
    int*    bsums   = (int*)alloc(1024);
    bf16_t* WTlin   = (bf16_t*)alloc((size_t)512 * 512 * 2);
    bf16_t* WT0     = (bf16_t*)alloc((size_t)512 * 512 * 2);
    bf16_t* WT1     = (bf16_t*)alloc((size_t)512 * 512 * 2);
    bf16_t* W2T     = (bf16_t*)alloc((size_t)NCLS * 512 * 2);
    int*    csr     = (int*)alloc((size_t)E * 4);
    float*  G       = (float*)alloc((size_t)NN * DDIM * 4);   // 204.8 MB

    float* H2 = (float*)d_in[0];   // feat dead after first GEMM (204.8 MB f32)
    float* P  = (float*)d_in[0];   // 16 MB logits scratch once H2 dead

    int eb   = (E + 255) / 256;
    int nb   = (NN + 255) / 256;
    int sb   = (NN + 1023) / 1024;
    dim3 g512((NN + 127) / 128, 4);
    dim3 g40 ((NN + 127) / 128, 1);
    int  sp  = (NN + 3) / 4;

    zero_int<<<nb, 256, 0, stream>>>(deg_out, NN);
    zero_int<<<nb, 256, 0, stream>>>(deg_in, NN);
    count_deg<<<eb, 256, 0, stream>>>(src, dst, deg_out, deg_in, E);
    norm_k<<<nb, 256, 0, stream>>>(deg_out, deg_in, nsrc, ndst, NN);

    scan_block<<<sb, 1024, 0, stream>>>(deg_in, row_ptr, bsums, NN);
    scan_block<<<1, 1024, 0, stream>>>(bsums, bsums, nullptr, sb);
    add_offs<<<sb, 1024, 0, stream>>>(row_ptr, cursor, bsums, NN);
    fill_csr<<<eb, 256, 0, stream>>>(src, dst, cursor, csr, E);

    transpose_w<<<(512 * 512 + 255) / 256, 256, 0, stream>>>(Wlin, WTlin, 512, 512);
    transpose_w<<<(512 * 512 + 255) / 256, 256, 0, stream>>>(W0, WT0, 512, 512);
    transpose_w<<<(512 * 512 + 255) / 256, 256, 0, stream>>>(W1, WT1, 512, 512);
    transpose_w<<<(512 * NCLS + 255) / 256, 256, 0, stream>>>(W2, W2T, 512, NCLS);

    // g0 = (X @ Wlin + blin) * norm_src          (feat dead after this)
    gemm_f32<<<g512, 256, 0, stream>>>(feat, WTlin, blin, nsrc, G, NN, 512, 0);
    // m0' = norm_dst * segsum(g0)
    spmm512<<<sp, 256, 0, stream>>>(G, csr, row_ptr, deg_in, ndst, H2, NN);
    // g1 = relu(m0' @ W0 + b0) * norm_src
    gemm_f32<<<g512, 256, 0, stream>>>(H2, WT0, b0, nsrc, G, NN, 512, 1);
    // m1' = norm_dst * segsum(g1)
    spmm512<<<sp, 256, 0, stream>>>(G, csr, row_ptr, deg_in, ndst, H2, NN);
    // g2 = relu(m1' @ W1 + b1) * norm_src
    gemm_f32<<<g512, 256, 0, stream>>>(H2, WT1, b1, nsrc, G, NN, 512, 1);
    // p = g2 @ W2   (GEMM commuted ahead of the final SpMM; H2 dead now)
    gemm_f32<<<g40, 256, 0, stream>>>(G, W2T, nullptr, nullptr, P, NN, NCLS, 0);
    // out = norm_dst * segsum(p) + b2
    spmm40<<<sp, 256, 0, stream>>>(P, csr, row_ptr, deg_in, ndst, b2, (float*)d_out, NN);
}

// Round 5
// 2549.006 us; speedup vs baseline: 1.4167x; 1.4167x over previous
//
#include <hip/hip_runtime.h>

#define NNODES 100000
#define DDIM   512
#define NCLS   40
#define KPAD   56   // LDS bf16 row stride: 112B = 16B-aligned rows, 2-way bank aliasing (free, m136)

typedef unsigned short bf16_t;
typedef short bf16x8 __attribute__((ext_vector_type(8)));   // gfx950 bf16 MFMA frag (guide §3)
typedef float f32x4  __attribute__((ext_vector_type(4)));

__device__ __forceinline__ float bf2f(unsigned int u){ return __uint_as_float(u << 16); }
__device__ __forceinline__ bf16_t f2bf(float f){
    unsigned int u = __float_as_uint(f);
    u += 0x7fffu + ((u >> 16) & 1u);   // RNE
    return (bf16_t)(u >> 16);
}

// ---------------- setup kernels ----------------

__global__ void zero_int(int* __restrict__ p, int n){
    int i = blockIdx.x * 256 + threadIdx.x;
    if (i < n) p[i] = 0;
}

__global__ void count_deg(const int* __restrict__ src, const int* __restrict__ dst,
                          int* __restrict__ dout, int* __restrict__ din, int E){
    int i = blockIdx.x * 256 + threadIdx.x;
    if (i < E){
        atomicAdd(&dout[src[i]], 1);
        atomicAdd(&din[dst[i]], 1);
    }
}

__global__ void norm_k(const int* __restrict__ dout, const int* __restrict__ din,
                       float* __restrict__ nsrc, float* __restrict__ ndst, int n){
    int i = blockIdx.x * 256 + threadIdx.x;
    if (i < n){
        nsrc[i] = rsqrtf(fmaxf((float)dout[i], 1.f));
        ndst[i] = rsqrtf(fmaxf((float)din[i], 1.f));
    }
}

__global__ void scan_block(const int* __restrict__ in, int* __restrict__ out,
                           int* __restrict__ bsums, int n){
    __shared__ int tmp[1024];
    int t = threadIdx.x;
    int i = blockIdx.x * 1024 + t;
    int v = (i < n) ? in[i] : 0;
    tmp[t] = v; __syncthreads();
    for (int off = 1; off < 1024; off <<= 1){
        int x = (t >= off) ? tmp[t - off] : 0;
        __syncthreads();
        tmp[t] += x;
        __syncthreads();
    }
    if (i < n) out[i] = tmp[t] - v;           // exclusive
    if (bsums && t == 1023) bsums[blockIdx.x] = tmp[1023];
}

__global__ void add_offs(int* __restrict__ rp, int* __restrict__ cur,
                         const int* __restrict__ bsums, int n){
    int i = blockIdx.x * 1024 + threadIdx.x;
    if (i < n){
        int v = rp[i] + bsums[blockIdx.x];
        rp[i] = v;
        cur[i] = v;
    }
}

__global__ void fill_csr(const int* __restrict__ src, const int* __restrict__ dst,
                         int* __restrict__ cur, int* __restrict__ csr, int E){
    int i = blockIdx.x * 256 + threadIdx.x;
    if (i < E){
        int pos = atomicAdd(&cur[dst[i]], 1);
        csr[pos] = src[i];
    }
}

// W f32 [K,N] row-major -> WT bf16 [N,K] row-major (fused transpose + cast)
__global__ void transpose_w(const float* __restrict__ W, bf16_t* __restrict__ WT, int K, int N){
    int i = blockIdx.x * 256 + threadIdx.x;
    if (i < K * N){
        int k = i / N, n = i - k * N;
        WT[n * K + k] = f2bf(W[i]);
    }
}

// ---------------- GEMM: C = act(A @ B + bias) * rowscale, C bf16 ----------------
// A [M,512] f32 (A_F32) or bf16; BT bf16 [N,512]; fp32 accumulate via mfma 16x16x32.
// 128x128 tile, 4 waves 2x2, 4x4 frags/wave.

template<bool A_F32>
__global__ __launch_bounds__(256) void gemm_k(
    const void* __restrict__ Aptr, const bf16_t* __restrict__ BT,
    const float* __restrict__ bias, const float* __restrict__ rowscale,
    bf16_t* __restrict__ Cmat, int M, int N, int doRelu)
{
    const int K = DDIM;
    __shared__ __align__(16) bf16_t As[128 * KPAD];
    __shared__ __align__(16) bf16_t Bs[128 * KPAD];
    int tid = threadIdx.x;
    int m0 = blockIdx.x * 128, n0 = blockIdx.y * 128;
    int wave = tid >> 6, lane = tid & 63;
    int wm = (wave >> 1) * 64, wn = (wave & 1) * 64;
    int quad = lane >> 4, r16 = lane & 15;

    f32x4 acc[4][4];
    #pragma unroll
    for (int i = 0; i < 4; i++)
        #pragma unroll
        for (int j = 0; j < 4; j++)
            acc[i][j] = (f32x4){0.f, 0.f, 0.f, 0.f};

    for (int k0 = 0; k0 < K; k0 += 32){
        float4 av[4];       // A_F32 path: 1024 float4 slots
        uint4  a16[2];      // bf16 path: 512 uint4 slots
        uint4  bv[2];
        if (A_F32){
            const float* A = (const float*)Aptr;
            #pragma unroll
            for (int j = 0; j < 4; j++){
                int slot = tid + j * 256;
                int row = slot >> 3, c4 = slot & 7;
                av[j] = (float4){0.f, 0.f, 0.f, 0.f};
                if (m0 + row < M) av[j] = *(const float4*)(A + (size_t)(m0 + row) * K + k0 + c4 * 4);
            }
        } else {
            const bf16_t* A = (const bf16_t*)Aptr;
            #pragma unroll
            for (int j = 0; j < 2; j++){
                int slot = tid + j * 256;
                int row = slot >> 2, c8 = slot & 3;
                a16[j] = (uint4){0, 0, 0, 0};
                if (m0 + row < M) a16[j] = *(const uint4*)(A + (size_t)(m0 + row) * K + k0 + c8 * 8);
            }
        }
        #pragma unroll
        for (int j = 0; j < 2; j++){
            int slot = tid + j * 256;
            int row = slot >> 2, c8 = slot & 3;
            bv[j] = (uint4){0, 0, 0, 0};
            if (n0 + row < N) bv[j] = *(const uint4*)(BT + (size_t)(n0 + row) * K + k0 + c8 * 8);
        }
        __syncthreads();
        if (A_F32){
            #pragma unroll
            for (int j = 0; j < 4; j++){
                int slot = tid + j * 256;
                int row = slot >> 3, c4 = slot & 7;
                ushort4 ap;
                ap.x = f2bf(av[j].x); ap.y = f2bf(av[j].y);
                ap.z = f2bf(av[j].z); ap.w = f2bf(av[j].w);
                *(ushort4*)&As[row * KPAD + c4 * 4] = ap;
            }
        } else {
            #pragma unroll
            for (int j = 0; j < 2; j++){
                int slot = tid + j * 256;
                int row = slot >> 2, c8 = slot & 3;
                *(uint4*)&As[row * KPAD + c8 * 8] = a16[j];
            }
        }
        #pragma unroll
        for (int j = 0; j < 2; j++){
            int slot = tid + j * 256;
            int row = slot >> 2, c8 = slot & 3;
            *(uint4*)&Bs[row * KPAD + c8 * 8] = bv[j];
        }
        __syncthreads();

        bf16x8 af[4], bfr[4];
        #pragma unroll
        for (int mi = 0; mi < 4; mi++)
            af[mi] = *(const bf16x8*)&As[(wm + mi * 16 + r16) * KPAD + quad * 8];
        #pragma unroll
        for (int ni = 0; ni < 4; ni++)
            bfr[ni] = *(const bf16x8*)&Bs[(wn + ni * 16 + r16) * KPAD + quad * 8];
        #pragma unroll
        for (int mi = 0; mi < 4; mi++)
            #pragma unroll
            for (int ni = 0; ni < 4; ni++)
                acc[mi][ni] = __builtin_amdgcn_mfma_f32_16x16x32_bf16(af[mi], bfr[ni], acc[mi][ni], 0, 0, 0);
    }

    // C/D layout: col = lane&15, row = quad*4 + reg  [m89/m91-verified]
    #pragma unroll
    for (int mi = 0; mi < 4; mi++){
        int rbase = m0 + wm + mi * 16 + quad * 4;
        #pragma unroll
        for (int ni = 0; ni < 4; ni++){
            int c = n0 + wn + ni * 16 + r16;
            if (c < N){
                float bvv = bias ? bias[c] : 0.f;
                #pragma unroll
                for (int r = 0; r < 4; r++){
                    int row = rbase + r;
                    if (row < M){
                        float val = acc[mi][ni][r] + bvv;
                        if (doRelu) val = fmaxf(val, 0.f);
                        if (rowscale) val *= rowscale[row];
                        Cmat[(size_t)row * N + c] = f2bf(val);
                    }
                }
            }
        }
    }
}

// ---------------- SpMM (CSR by dst): out[v] = ndst[v]*sum g[u], 512-dim bf16 ----------------
// one wave per node; lane holds 8 bf16 (16B) -> per edge the wave reads one contiguous 1 KB row.

__global__ __launch_bounds__(256) void spmm512(
    const bf16_t* __restrict__ g, const int* __restrict__ csr,
    const int* __restrict__ rp, const int* __restrict__ deg,
    const float* __restrict__ ndst, bf16_t* __restrict__ outm, int nn)
{
    int wave = threadIdx.x >> 6, lane = threadIdx.x & 63;
    int v = blockIdx.x * 4 + wave;
    if (v >= nn) return;
    int start = rp[v], cnt = deg[v];
    float acc[8] = {0,0,0,0,0,0,0,0};
    const bf16_t* base = g + (size_t)lane * 8;
    for (int e = 0; e < cnt; e++){
        int u = csr[start + e];
        uint4 d = *(const uint4*)(base + (size_t)u * DDIM);
        acc[0] += bf2f(d.x & 0xffffu); acc[1] += bf2f(d.x >> 16);
        acc[2] += bf2f(d.y & 0xffffu); acc[3] += bf2f(d.y >> 16);
        acc[4] += bf2f(d.z & 0xffffu); acc[5] += bf2f(d.z >> 16);
        acc[6] += bf2f(d.w & 0xffffu); acc[7] += bf2f(d.w >> 16);
    }
    float s = ndst[v];
    uint4 o;
    o.x = (unsigned)f2bf(acc[0] * s) | ((unsigned)f2bf(acc[1] * s) << 16);
    o.y = (unsigned)f2bf(acc[2] * s) | ((unsigned)f2bf(acc[3] * s) << 16);
    o.z = (unsigned)f2bf(acc[4] * s) | ((unsigned)f2bf(acc[5] * s) << 16);
    o.w = (unsigned)f2bf(acc[6] * s) | ((unsigned)f2bf(acc[7] * s) << 16);
    *(uint4*)(outm + (size_t)v * DDIM + lane * 8) = o;
}

// 40-dim SpMM for the last layer (GEMM commuted ahead of it): out = ndst*sum + b2, f32 out
__global__ __launch_bounds__(256) void spmm40(
    const bf16_t* __restrict__ p40, const int* __restrict__ csr,
    const int* __restrict__ rp, const int* __restrict__ deg,
    const float* __restrict__ ndst, const float* __restrict__ b2,
    float* __restrict__ out, int nn)
{
    int wave = threadIdx.x >> 6, lane = threadIdx.x & 63;
    int v = blockIdx.x * 4 + wave;
    if (v >= nn || lane >= NCLS) return;
    int start = rp[v], cnt = deg[v];
    float acc = 0.f;
    for (int e = 0; e < cnt; e++){
        int u = csr[start + e];
        acc += bf2f((unsigned)p40[(size_t)u * NCLS + lane]);
    }
    out[(size_t)v * NCLS + lane] = acc * ndst[v] + b2[lane];
}

// ---------------- launch ----------------
// bf16 intermediates: G (d_ws, 102.4 MB) is the spmm gather source -> fully
// L3-resident (256 MB). H2/P live in d_in[0] (restored pre-launch => legal
// scratch after its last read). ws use ~119 MB.

extern "C" void kernel_launch(void* const* d_in, const int* in_sizes, int n_in,
                              void* d_out, int out_size, void* d_ws, size_t ws_size,
                              hipStream_t stream)
{
    const float* feat = (const float*)d_in[0];
    const int*   src  = (const int*)d_in[1];
    const int*   dst  = (const int*)d_in[2];
    const float* Wlin = (const float*)d_in[3];
    const float* blin = (const float*)d_in[4];
    const float* W0   = (const float*)d_in[5];
    const float* b0   = (const float*)d_in[6];
    const float* W1   = (const float*)d_in[7];
    const float* b1   = (const float*)d_in[8];
    const float* W2   = (const float*)d_in[9];
    const float* b2   = (const float*)d_in[10];

    const int NN = NNODES;
    const int E  = in_sizes[1];

    char* wsp = (char*)d_ws;
    auto alloc = [&](size_t bytes) -> char* {
        char* r = wsp;
        wsp += (bytes + 255) & ~(size_t)255;
        return r;
    };
    int*    deg_out = (int*)alloc((size_t)NN * 4);
    int*    deg_in  = (int*)alloc((size_t)NN * 4);
    float*  nsrc    = (float*)alloc((size_t)NN * 4);
    float*  ndst    = (float*)alloc((size_t)NN * 4);
    int*    row_ptr = (int*)alloc((size_t)NN * 4);
    int*    cursor  = (int*)alloc((size_t)NN * 4);
    int*    bsums   = (int*)alloc(1024);
    bf16_t* WTlin   = (bf16_t*)alloc((size_t)512 * 512 * 2);
    bf16_t* WT0     = (bf16_t*)alloc((size_t)512 * 512 * 2);
    bf16_t* WT1     = (bf16_t*)alloc((size_t)512 * 512 * 2);
    bf16_t* W2T     = (bf16_t*)alloc((size_t)NCLS * 512 * 2);
    int*    csr     = (int*)alloc((size_t)E * 4);
    bf16_t* G       = (bf16_t*)alloc((size_t)NN * DDIM * 2);   // 102.4 MB, L3-resident

    bf16_t* H2 = (bf16_t*)d_in[0];   // feat dead after first GEMM
    bf16_t* P  = (bf16_t*)d_in[0];   // 8 MB logits scratch once H2 dead

    int eb   = (E + 255) / 256;
    int nb   = (NN + 255) / 256;
    int sb   = (NN + 1023) / 1024;
    dim3 g512((NN + 127) / 128, 4);
    dim3 g40 ((NN + 127) / 128, 1);
    int  sp  = (NN + 3) / 4;

    zero_int<<<nb, 256, 0, stream>>>(deg_out, NN);
    zero_int<<<nb, 256, 0, stream>>>(deg_in, NN);
    count_deg<<<eb, 256, 0, stream>>>(src, dst, deg_out, deg_in, E);
    norm_k<<<nb, 256, 0, stream>>>(deg_out, deg_in, nsrc, ndst, NN);

    scan_block<<<sb, 1024, 0, stream>>>(deg_in, row_ptr, bsums, NN);
    scan_block<<<1, 1024, 0, stream>>>(bsums, bsums, nullptr, sb);
    add_offs<<<sb, 1024, 0, stream>>>(row_ptr, cursor, bsums, NN);
    fill_csr<<<eb, 256, 0, stream>>>(src, dst, cursor, csr, E);

    transpose_w<<<(512 * 512 + 255) / 256, 256, 0, stream>>>(Wlin, WTlin, 512, 512);
    transpose_w<<<(512 * 512 + 255) / 256, 256, 0, stream>>>(W0, WT0, 512, 512);
    transpose_w<<<(512 * 512 + 255) / 256, 256, 0, stream>>>(W1, WT1, 512, 512);
    transpose_w<<<(512 * NCLS + 255) / 256, 256, 0, stream>>>(W2, W2T, 512, NCLS);

    // g0 = (X @ Wlin + blin) * norm_src          (feat dead after this)
    gemm_k<true ><<<g512, 256, 0, stream>>>(feat, WTlin, blin, nsrc, G, NN, 512, 0);
    // m0' = norm_dst * segsum(g0)
    spmm512<<<sp, 256, 0, stream>>>(G, csr, row_ptr, deg_in, ndst, H2, NN);
    // g1 = relu(m0' @ W0 + b0) * norm_src
    gemm_k<false><<<g512, 256, 0, stream>>>(H2, WT0, b0, nsrc, G, NN, 512, 1);
    // m1' = norm_dst * segsum(g1)
    spmm512<<<sp, 256, 0, stream>>>(G, csr, row_ptr, deg_in, ndst, H2, NN);
    // g2 = relu(m1' @ W1 + b1) * norm_src
    gemm_k<false><<<g512, 256, 0, stream>>>(H2, WT1, b1, nsrc, G, NN, 512, 1);
    // p = g2 @ W2   (GEMM commuted ahead of the final SpMM; H2 dead now)
    gemm_k<false><<<g40, 256, 0, stream>>>(G, W2T, nullptr, nullptr, P, NN, NCLS, 0);
    // out = norm_dst * segsum(p) + b2
    spmm40<<<sp, 256, 0, stream>>>(P, csr, row_ptr, deg_in, ndst, b2, (float*)d_out, NN);
}